// Round 3
// baseline (934.147 us; speedup 1.0000x reference)
//
#include <hip/hip_runtime.h>

#define NPTS 4096
#define CH 64
#define BATCH 8
#define KNN 20
#define NEG_SLOPE 0.2f
#define EPSV 1e-5f
#define NEG_INF (-3.4e38f)

typedef float v2f __attribute__((ext_vector_type(2)));

// ---------------- K0: xx[b,n] = sum_c x[b,c,n]^2 ----------------
__global__ void k_xx(const float* __restrict__ x, float* __restrict__ xx) {
  int t = blockIdx.x * 256 + threadIdx.x;          // [0, B*N)
  int b = t >> 12, n = t & (NPTS - 1);
  const float* xp = x + ((size_t)b * CH * NPTS) + n;
  float s = 0.f;
#pragma unroll
  for (int c = 0; c < CH; ++c) { float v = xp[(size_t)c * NPTS]; s = fmaf(v, v, s); }
  xx[t] = s;
}

// ---------------- K2: P'[t,o], Q'[t,o] ----------------
__global__ void k_pq(const float* __restrict__ x, const float* __restrict__ W,
                     const float* __restrict__ gamma, const float* __restrict__ beta,
                     const float* __restrict__ rmean, const float* __restrict__ rvar,
                     float* __restrict__ P, float* __restrict__ Q) {
  __shared__ float Ws1[CH * CH];   // [c][o], W1*inv
  __shared__ float Wsd[CH * CH];   // [c][o], (W2-W1)*inv
  int tid = threadIdx.x;
  for (int i = tid; i < CH * CH; i += 256) {
    int o = i & 63, c = i >> 6;
    float s = gamma[o] * rsqrtf(rvar[o] + EPSV);
    float w1 = W[o * 128 + c], w2 = W[o * 128 + 64 + c];
    Ws1[c * 64 + o] = w1 * s;
    Wsd[c * 64 + o] = (w2 - w1) * s;
  }
  __syncthreads();
  int o = tid & 63, ng = tid >> 6;
  float s = gamma[o] * rsqrtf(rvar[o] + EPSV);
  float shift = beta[o] - rmean[o] * s;
  int base = blockIdx.x * 16;
  for (int rp = 0; rp < 4; ++rp) {
    int t = base + rp * 4 + ng;                    // row in [0, B*N)
    int b = t >> 12, n = t & (NPTS - 1);
    const float* xp = x + ((size_t)b * CH * NPTS) + n;
    float accp = 0.f, accq = 0.f;
#pragma unroll 8
    for (int c = 0; c < CH; ++c) {
      float xv = xp[(size_t)c * NPTS];
      accp = fmaf(xv, Ws1[c * 64 + o], accp);
      accq = fmaf(xv, Wsd[c * 64 + o], accq);
    }
    P[(size_t)t * 64 + o] = accp;
    Q[(size_t)t * 64 + o] = accq + shift;
  }
}

// ---------------- K1 helpers ----------------
// async global->LDS, 16B per lane. LDS dest is wave-uniform base + lane*16.
__device__ __forceinline__ void gload_lds16(const float* g, float* l) {
  __builtin_amdgcn_global_load_lds(
      (const __attribute__((address_space(1))) void*)g,
      (__attribute__((address_space(3))) void*)l, 16, 0, 0);
}

// stage one 64ch x 128col B-tile (32 KB) async; no VGPR round-trip.
__device__ __forceinline__ void stage_b(const float* xb, int mcol, float* Bdst,
                                        int w, int lane) {
#pragma unroll
  for (int k = 0; k < 8; ++k) {
    int q = w + 4 * k;
    int c = 2 * q + (lane >> 5);
    int cm = (lane & 31) << 2;
    gload_lds16(xb + (size_t)c * NPTS + mcol + cm, Bdst + q * 256);
  }
}

// packed fp32 fma: element-wise IEEE fma -> bit-identical to scalar chain
__device__ __forceinline__ v2f fma2(float a, v2f b, v2f c) {
#if __has_builtin(__builtin_elementwise_fma)
  v2f av; av.x = a; av.y = a;
  return __builtin_elementwise_fma(av, b, c);
#else
  v2f r; r.x = fmaf(a, b.x, c.x); r.y = fmaf(a, b.y, c.y); return r;
#endif
}

// GEMM (16 rows x 2 cols per thread, lane==col within each 64-group) +
// register-direct ballot top-k insert.
//  * A fragments read from GLOBAL with wave-uniform addresses (one coalesced
//    64B L1/L2 transaction, VMEM pipe / vmcnt) -> the 4 broadcast
//    ds_read_b128 per c-step that dominated the LDS pipe are gone.
//  * next-tile stage_b is issued AFTER the GEMM's A-loads (in-order vmcnt
//    never blocks an A-consume on the prefetch) and BEFORE selection
//    (selection covers the stage latency).
//  * threshold cached in a register, refreshed only after an insertion ->
//    removes the per-row-group ds_bpermute. Ballot gate semantics identical.
//  * fp op order identical to passing kernels -> indices bit-identical.
__device__ __forceinline__ void tile_work(const float* Bc, const float* xb,
                                          const float* xxb, int n0, int m0,
                                          int w, int lane,
                                          const float (&xnr)[16],
                                          float (&val)[16], int (&idx)[16],
                                          float (&thd)[16],
                                          const float* stage_src, int stage_mcol,
                                          float* stage_dst) {
  float xm0 = xxb[m0 + lane];
  float xm1 = xxb[m0 + 64 + lane];
  const float* Ag = xb + n0 + 16 * w;              // + c*NPTS per channel

  v2f acc[16];
#pragma unroll
  for (int r = 0; r < 16; ++r) { acc[r].x = 0.f; acc[r].y = 0.f; }

#pragma unroll 4
  for (int c = 0; c < CH; ++c) {
    const float* Aw = Ag + (size_t)c * NPTS;       // wave-uniform address
    float4 A0 = *(const float4*)(Aw);
    float4 A1 = *(const float4*)(Aw + 4);
    float4 A2 = *(const float4*)(Aw + 8);
    float4 A3 = *(const float4*)(Aw + 12);
    v2f bb; bb.x = Bc[c * 128 + lane]; bb.y = Bc[c * 128 + 64 + lane];
    acc[0]  = fma2(A0.x, bb, acc[0]);
    acc[1]  = fma2(A0.y, bb, acc[1]);
    acc[2]  = fma2(A0.z, bb, acc[2]);
    acc[3]  = fma2(A0.w, bb, acc[3]);
    acc[4]  = fma2(A1.x, bb, acc[4]);
    acc[5]  = fma2(A1.y, bb, acc[5]);
    acc[6]  = fma2(A1.z, bb, acc[6]);
    acc[7]  = fma2(A1.w, bb, acc[7]);
    acc[8]  = fma2(A2.x, bb, acc[8]);
    acc[9]  = fma2(A2.y, bb, acc[9]);
    acc[10] = fma2(A2.z, bb, acc[10]);
    acc[11] = fma2(A2.w, bb, acc[11]);
    acc[12] = fma2(A3.x, bb, acc[12]);
    acc[13] = fma2(A3.y, bb, acc[13]);
    acc[14] = fma2(A3.z, bb, acc[14]);
    acc[15] = fma2(A3.w, bb, acc[15]);
  }

  // issue next-tile prefetch now: after A-loads (vmcnt ordering), before
  // selection (covers its latency). Writes the OTHER B buffer.
  if (stage_dst) stage_b(stage_src, stage_mcol, stage_dst, w, lane);

#pragma unroll
  for (int r = 0; r < 16; ++r) {
    {
      float d = (2.f * acc[r].x - xnr[r]) - xm0;
      unsigned long long hit = __ballot(d > thd[r]);
      bool any = hit != 0ull;
      int mg = m0;
      while (hit) {
        int j = __builtin_ctzll(hit);
        hit &= hit - 1;
        float cv = __shfl(d, j);
        int cm = mg + j;
        unsigned long long km = __ballot(val[r] >= cv);
        int cnt = __popcll(km);
        float sv = __shfl_up(val[r], 1);
        int si = __shfl_up(idx[r], 1);
        if (lane >= cnt) {
          val[r] = (lane == cnt) ? cv : sv;
          idx[r] = (lane == cnt) ? cm : si;
        }
      }
      if (any) thd[r] = __shfl(val[r], KNN - 1);
    }
    {
      float d = (2.f * acc[r].y - xnr[r]) - xm1;
      unsigned long long hit = __ballot(d > thd[r]);
      bool any = hit != 0ull;
      int mg = m0 + 64;
      while (hit) {
        int j = __builtin_ctzll(hit);
        hit &= hit - 1;
        float cv = __shfl(d, j);
        int cm = mg + j;
        unsigned long long km = __ballot(val[r] >= cv);
        int cnt = __popcll(km);
        float sv = __shfl_up(val[r], 1);
        int si = __shfl_up(idx[r], 1);
        if (lane >= cnt) {
          val[r] = (lane == cnt) ? cv : sv;
          idx[r] = (lane == cnt) ? cm : si;
        }
      }
      if (any) thd[r] = __shfl(val[r], KNN - 1);
    }
  }
}

// ---------------- K1: fused distance-GEMM + register-direct top-20 ----------
// LDS = B0 32KB + B1 32KB = 64KB (As deleted; A read from global).
__launch_bounds__(256, 2)
__global__ void k_knn(const float* __restrict__ x, const float* __restrict__ xx,
                      int* __restrict__ idxout) {
  __shared__ float B0[64 * 128];
  __shared__ float B1[64 * 128];
  int tid = threadIdx.x;
  int nb = blockIdx.x, b = blockIdx.y;
  int n0 = nb * 64;
  const float* xb = x + (size_t)b * CH * NPTS;
  const float* xxb = xx + b * NPTS;
  int lane = tid & 63;
  int w = tid >> 6;

  // stage B tile 0 async
  stage_b(xb, 0, B0, w, lane);

  float xnr[16];
#pragma unroll
  for (int r = 0; r < 16; ++r) xnr[r] = xxb[n0 + 16 * w + r];

  float val[16]; int idx[16]; float thd[16];
#pragma unroll
  for (int r = 0; r < 16; ++r) { val[r] = NEG_INF; idx[r] = 0; thd[r] = NEG_INF; }

  __syncthreads();                                 // drains vmcnt: B0 ready

#pragma unroll 1
  for (int mt = 0; mt < NPTS / 128; mt += 2) {
    // tile mt from B0; prefetch mt+1 -> B1 inside (post-GEMM, pre-selection)
    tile_work(B0, xb, xxb, n0, mt * 128, w, lane, xnr, val, idx, thd,
              xb, (mt + 1) * 128, B1);
    __syncthreads();                               // B1 staged; B0 readers done

    // tile mt+1 from B1; prefetch mt+2 -> B0 (unless last pair)
    tile_work(B1, xb, xxb, n0, (mt + 1) * 128, w, lane, xnr, val, idx, thd,
              xb, (mt + 2) * 128, (mt + 2 < NPTS / 128) ? B0 : nullptr);
    __syncthreads();                               // B0 staged; B1 readers done
  }

  // emit: lane l (<20) holds l-th best index for row 16w+r
#pragma unroll
  for (int r = 0; r < 16; ++r) {
    int n = n0 + 16 * w + r;
    if (lane < KNN) idxout[(size_t)(b * NPTS + n) * KNN + lane] = idx[r];
  }
}

// ---------------- K3: gather + max + leaky, transpose to (B,O,N) ----------------
__global__ void k_out(const float* __restrict__ P, const float* __restrict__ Q,
                      const int* __restrict__ idx, float* __restrict__ out) {
  __shared__ float T[64 * 65];
  int tid = threadIdx.x;
  int nb = blockIdx.x, b = blockIdx.y;
  int n0 = nb * 64;
  int o = tid & 63, ng = tid >> 6;
  const float* Pb = P + (size_t)b * NPTS * 64;
  for (int p = 0; p < 16; ++p) {
    int nl = p * 4 + ng;
    int n = n0 + nl;
    const int* ip = idx + (size_t)(b * NPTS + n) * KNN;
    float mx = NEG_INF;
#pragma unroll
    for (int k = 0; k < KNN; ++k) {
      int id = ip[k];
      float v = Pb[(size_t)id * 64 + o];
      mx = fmaxf(mx, v);
    }
    float z = mx + Q[(size_t)(b * NPTS + n) * 64 + o];
    z = (z >= 0.f) ? z : NEG_SLOPE * z;
    T[o * 65 + nl] = z;
  }
  __syncthreads();
  float* ob = out + (size_t)b * 64 * NPTS + n0;
  int nl = tid & 63;
  for (int w = 0; w < 16; ++w) {
    int oo = w * 4 + ng;
    ob[(size_t)oo * NPTS + nl] = T[oo * 65 + nl];
  }
}

extern "C" void kernel_launch(void* const* d_in, const int* in_sizes, int n_in,
                              void* d_out, int out_size, void* d_ws, size_t ws_size,
                              hipStream_t stream) {
  const float* x     = (const float*)d_in[0];
  const float* W     = (const float*)d_in[1];
  const float* gamma = (const float*)d_in[2];
  const float* beta  = (const float*)d_in[3];
  const float* rmean = (const float*)d_in[4];
  const float* rvar  = (const float*)d_in[5];
  float* out = (float*)d_out;

  float* xx = (float*)d_ws;                        // 32768 floats
  float* P  = xx + 32768;                          // 2097152 floats
  float* Q  = P + 2097152;                         // 2097152 floats
  int*   idx = (int*)(Q + 2097152);                // 655360 ints

  k_xx<<<BATCH * NPTS / 256, 256, 0, stream>>>(x, xx);
  k_pq<<<BATCH * NPTS / 16, 256, 0, stream>>>(x, W, gamma, beta, rmean, rvar, P, Q);
  k_knn<<<dim3(NPTS / 64, BATCH), 256, 0, stream>>>(x, xx, idx);
  k_out<<<dim3(NPTS / 64, BATCH), 256, 0, stream>>>(P, Q, idx, out);
}

// Round 4
// 755.155 us; speedup vs baseline: 1.2370x; 1.2370x over previous
//
#include <hip/hip_runtime.h>

#define NPTS 4096
#define CH 64
#define BATCH 8
#define KNN 20
#define NEG_SLOPE 0.2f
#define EPSV 1e-5f
#define NEG_INF (-3.4e38f)

typedef float v2f __attribute__((ext_vector_type(2)));

// ---------------- K0: xx[b,n] = sum_c x[b,c,n]^2 ----------------
__global__ void k_xx(const float* __restrict__ x, float* __restrict__ xx) {
  int t = blockIdx.x * 256 + threadIdx.x;          // [0, B*N)
  int b = t >> 12, n = t & (NPTS - 1);
  const float* xp = x + ((size_t)b * CH * NPTS) + n;
  float s = 0.f;
#pragma unroll
  for (int c = 0; c < CH; ++c) { float v = xp[(size_t)c * NPTS]; s = fmaf(v, v, s); }
  xx[t] = s;
}

// ---------------- K2: P'[t,o], Q'[t,o] ----------------
__global__ void k_pq(const float* __restrict__ x, const float* __restrict__ W,
                     const float* __restrict__ gamma, const float* __restrict__ beta,
                     const float* __restrict__ rmean, const float* __restrict__ rvar,
                     float* __restrict__ P, float* __restrict__ Q) {
  __shared__ float Ws1[CH * CH];   // [c][o], W1*inv
  __shared__ float Wsd[CH * CH];   // [c][o], (W2-W1)*inv
  int tid = threadIdx.x;
  for (int i = tid; i < CH * CH; i += 256) {
    int o = i & 63, c = i >> 6;
    float s = gamma[o] * rsqrtf(rvar[o] + EPSV);
    float w1 = W[o * 128 + c], w2 = W[o * 128 + 64 + c];
    Ws1[c * 64 + o] = w1 * s;
    Wsd[c * 64 + o] = (w2 - w1) * s;
  }
  __syncthreads();
  int o = tid & 63, ng = tid >> 6;
  float s = gamma[o] * rsqrtf(rvar[o] + EPSV);
  float shift = beta[o] - rmean[o] * s;
  int base = blockIdx.x * 16;
  for (int rp = 0; rp < 4; ++rp) {
    int t = base + rp * 4 + ng;                    // row in [0, B*N)
    int b = t >> 12, n = t & (NPTS - 1);
    const float* xp = x + ((size_t)b * CH * NPTS) + n;
    float accp = 0.f, accq = 0.f;
#pragma unroll 8
    for (int c = 0; c < CH; ++c) {
      float xv = xp[(size_t)c * NPTS];
      accp = fmaf(xv, Ws1[c * 64 + o], accp);
      accq = fmaf(xv, Wsd[c * 64 + o], accq);
    }
    P[(size_t)t * 64 + o] = accp;
    Q[(size_t)t * 64 + o] = accq + shift;
  }
}

// ---------------- K1 helpers ----------------
// async global->LDS, 16B per lane. LDS dest = wave-uniform base + lane*16.
__device__ __forceinline__ void gload_lds16(const float* g, float* l) {
  __builtin_amdgcn_global_load_lds(
      (const __attribute__((address_space(1))) void*)g,
      (__attribute__((address_space(3))) void*)l, 16, 0, 0);
}

// stage one 64ch x 256col B-tile (64 KB) async. One wave-instr covers one
// row (256 floats): lane l -> floats 4l..4l+3. Wave w handles rows w, w+8...
__device__ __forceinline__ void stage_b(const float* xb, int mcol, float* Bdst,
                                        int w, int lane) {
#pragma unroll
  for (int k = 0; k < 8; ++k) {
    int c = w + 8 * k;
    gload_lds16(xb + (size_t)c * NPTS + mcol + 4 * lane, Bdst + c * 256);
  }
}

// packed fp32 fma: element-wise IEEE fma -> bit-identical to scalar chain
__device__ __forceinline__ v2f fma2(float a, v2f b, v2f c) {
#if __has_builtin(__builtin_elementwise_fma)
  v2f av; av.x = a; av.y = a;
  return __builtin_elementwise_fma(av, b, c);
#else
  v2f r; r.x = fmaf(a, b.x, c.x); r.y = fmaf(a, b.y, c.y); return r;
#endif
}

// GEMM (8 rows x 4 cols per thread; lane==col within each 64-group) +
// register-direct ballot top-k insert. 8 rows/wave halves the broadcast
// ds_read_b128 A-traffic per wave; 256 cols/wave amortizes it over 2x the
// FMA work -> ~2.5x more work per LDS-pipe cycle than the 16x2 layout.
// fp op order per output element identical to all prior passing kernels.
__device__ __forceinline__ void tile_work(const float* Bc, const float* As,
                                          const float* xxb, int m0, int w, int lane,
                                          const float (&xnr)[8],
                                          float (&val)[8], int (&idx)[8],
                                          float (&thd)[8],
                                          const float* stage_src, int stage_mcol,
                                          float* stage_dst) {
  // xm loads FIRST so their vmcnt-consume doesn't wait on the stage below
  float xm[4];
#pragma unroll
  for (int g = 0; g < 4; ++g) xm[g] = xxb[m0 + 64 * g + lane];

  // issue next-tile async stage now: GEMM+selection covers its latency;
  // barrier at tile end drains it.
  if (stage_dst) stage_b(stage_src, stage_mcol, stage_dst, w, lane);

  const float* Aw = As + 8 * w;

  v2f accA[8], accB[8];
#pragma unroll
  for (int r = 0; r < 8; ++r) {
    accA[r].x = 0.f; accA[r].y = 0.f; accB[r].x = 0.f; accB[r].y = 0.f;
  }

#pragma unroll 4
  for (int c = 0; c < CH; ++c) {
    float4 A0 = *(const float4*)(Aw + c * 64);       // rows 8w..8w+3 (broadcast)
    float4 A1 = *(const float4*)(Aw + c * 64 + 4);   // rows 8w+4..8w+7
    v2f bbA, bbB;
    bbA.x = Bc[c * 256 + lane];
    bbA.y = Bc[c * 256 + 64 + lane];
    bbB.x = Bc[c * 256 + 128 + lane];
    bbB.y = Bc[c * 256 + 192 + lane];
    accA[0] = fma2(A0.x, bbA, accA[0]);  accB[0] = fma2(A0.x, bbB, accB[0]);
    accA[1] = fma2(A0.y, bbA, accA[1]);  accB[1] = fma2(A0.y, bbB, accB[1]);
    accA[2] = fma2(A0.z, bbA, accA[2]);  accB[2] = fma2(A0.z, bbB, accB[2]);
    accA[3] = fma2(A0.w, bbA, accA[3]);  accB[3] = fma2(A0.w, bbB, accB[3]);
    accA[4] = fma2(A1.x, bbA, accA[4]);  accB[4] = fma2(A1.x, bbB, accB[4]);
    accA[5] = fma2(A1.y, bbA, accA[5]);  accB[5] = fma2(A1.y, bbB, accB[5]);
    accA[6] = fma2(A1.z, bbA, accA[6]);  accB[6] = fma2(A1.z, bbB, accB[6]);
    accA[7] = fma2(A1.w, bbA, accA[7]);  accB[7] = fma2(A1.w, bbB, accB[7]);
  }

  // selection: groups g=0..3 ascending (cols m0+64g+lane), ctz-ascending
  // within a group -> candidate stream per row identical to prior kernels.
#pragma unroll
  for (int r = 0; r < 8; ++r) {
#pragma unroll
    for (int g = 0; g < 4; ++g) {
      float a = (g < 2) ? ((g == 0) ? accA[r].x : accA[r].y)
                        : ((g == 2) ? accB[r].x : accB[r].y);
      float d = (2.f * a - xnr[r]) - xm[g];
      unsigned long long hit = __ballot(d > thd[r]);
      bool any = hit != 0ull;
      int mg = m0 + 64 * g;
      while (hit) {
        int j = __builtin_ctzll(hit);
        hit &= hit - 1;
        float cv = __shfl(d, j);
        int cm = mg + j;
        unsigned long long km = __ballot(val[r] >= cv);
        int cnt = __popcll(km);
        float sv = __shfl_up(val[r], 1);
        int si = __shfl_up(idx[r], 1);
        if (lane >= cnt) {
          val[r] = (lane == cnt) ? cv : sv;
          idx[r] = (lane == cnt) ? cm : si;
        }
      }
      if (any) thd[r] = __shfl(val[r], KNN - 1);
    }
  }
}

// ---------------- K1: fused distance-GEMM + register-direct top-20 ----------
// 512 threads, 8 waves; wave w owns rows 8w..8w+7; tile 64 rows x 256 cols.
// LDS = As 16KB + B0 64KB + B1 64KB = 144KB -> 1 block/CU, 8 waves/CU
// (2/SIMD, same as before). One barrier per tile.
__launch_bounds__(512, 2)
__global__ void k_knn(const float* __restrict__ x, const float* __restrict__ xx,
                      int* __restrict__ idxout) {
  __shared__ float As[64 * 64];
  __shared__ float B0[64 * 256];
  __shared__ float B1[64 * 256];
  int tid = threadIdx.x;
  int nb = blockIdx.x, b = blockIdx.y;
  int n0 = nb * 64;
  const float* xb = x + (size_t)b * CH * NPTS;
  const float* xxb = xx + b * NPTS;
  int lane = tid & 63;
  int w = tid >> 6;

  // stage B tile 0 async (64 KB)
  stage_b(xb, 0, B0, w, lane);

  // stage A-tile [c][n]: 4096 floats, 512 threads x 8 floats
  {
    int c = tid >> 3, n4 = (tid & 7) << 3;
    float4 v0 = *(const float4*)(xb + (size_t)c * NPTS + n0 + n4);
    float4 v1 = *(const float4*)(xb + (size_t)c * NPTS + n0 + n4 + 4);
    *(float4*)(As + c * 64 + n4) = v0;
    *(float4*)(As + c * 64 + n4 + 4) = v1;
  }

  float xnr[8];
#pragma unroll
  for (int r = 0; r < 8; ++r) xnr[r] = xxb[n0 + 8 * w + r];

  float val[8]; int idx[8]; float thd[8];
#pragma unroll
  for (int r = 0; r < 8; ++r) { val[r] = NEG_INF; idx[r] = 0; thd[r] = NEG_INF; }

  __syncthreads();                                 // drains vmcnt: B0 + As ready

#pragma unroll 1
  for (int mt = 0; mt < NPTS / 256; mt += 2) {
    // tile mt from B0; stage mt+1 -> B1 at start (covered by GEMM+selection)
    tile_work(B0, As, xxb, mt * 256, w, lane, xnr, val, idx, thd,
              xb, (mt + 1) * 256, B1);
    __syncthreads();                               // B1 staged; B0 readers done

    // tile mt+1 from B1; stage mt+2 -> B0 (unless last pair)
    tile_work(B1, As, xxb, (mt + 1) * 256, w, lane, xnr, val, idx, thd,
              xb, (mt + 2) * 256, (mt + 2 < NPTS / 256) ? B0 : nullptr);
    __syncthreads();                               // B0 staged; B1 readers done
  }

  // emit: lane l (<20) holds l-th best index for row 8w+r
#pragma unroll
  for (int r = 0; r < 8; ++r) {
    int n = n0 + 8 * w + r;
    if (lane < KNN) idxout[(size_t)(b * NPTS + n) * KNN + lane] = idx[r];
  }
}

// ---------------- K3: gather + max + leaky, transpose to (B,O,N) ----------------
__global__ void k_out(const float* __restrict__ P, const float* __restrict__ Q,
                      const int* __restrict__ idx, float* __restrict__ out) {
  __shared__ float T[64 * 65];
  int tid = threadIdx.x;
  int nb = blockIdx.x, b = blockIdx.y;
  int n0 = nb * 64;
  int o = tid & 63, ng = tid >> 6;
  const float* Pb = P + (size_t)b * NPTS * 64;
  for (int p = 0; p < 16; ++p) {
    int nl = p * 4 + ng;
    int n = n0 + nl;
    const int* ip = idx + (size_t)(b * NPTS + n) * KNN;
    float mx = NEG_INF;
#pragma unroll
    for (int k = 0; k < KNN; ++k) {
      int id = ip[k];
      float v = Pb[(size_t)id * 64 + o];
      mx = fmaxf(mx, v);
    }
    float z = mx + Q[(size_t)(b * NPTS + n) * 64 + o];
    z = (z >= 0.f) ? z : NEG_SLOPE * z;
    T[o * 65 + nl] = z;
  }
  __syncthreads();
  float* ob = out + (size_t)b * 64 * NPTS + n0;
  int nl = tid & 63;
  for (int w = 0; w < 16; ++w) {
    int oo = w * 4 + ng;
    ob[(size_t)oo * NPTS + nl] = T[oo * 65 + nl];
  }
}

extern "C" void kernel_launch(void* const* d_in, const int* in_sizes, int n_in,
                              void* d_out, int out_size, void* d_ws, size_t ws_size,
                              hipStream_t stream) {
  const float* x     = (const float*)d_in[0];
  const float* W     = (const float*)d_in[1];
  const float* gamma = (const float*)d_in[2];
  const float* beta  = (const float*)d_in[3];
  const float* rmean = (const float*)d_in[4];
  const float* rvar  = (const float*)d_in[5];
  float* out = (float*)d_out;

  float* xx = (float*)d_ws;                        // 32768 floats
  float* P  = xx + 32768;                          // 2097152 floats
  float* Q  = P + 2097152;                         // 2097152 floats
  int*   idx = (int*)(Q + 2097152);                // 655360 ints

  k_xx<<<BATCH * NPTS / 256, 256, 0, stream>>>(x, xx);
  k_pq<<<BATCH * NPTS / 16, 256, 0, stream>>>(x, W, gamma, beta, rmean, rvar, P, Q);
  k_knn<<<dim3(NPTS / 64, BATCH), 512, 0, stream>>>(x, xx, idx);
  k_out<<<dim3(NPTS / 64, BATCH), 256, 0, stream>>>(P, Q, idx, out);
}

// Round 5
// 671.187 us; speedup vs baseline: 1.3918x; 1.1251x over previous
//
#include <hip/hip_runtime.h>

#define NPTS 4096
#define CH 64
#define BATCH 8
#define KNN 20
#define NEG_SLOPE 0.2f
#define EPSV 1e-5f
#define NEG_INF (-3.4e38f)

typedef float v2f __attribute__((ext_vector_type(2)));

// ---------------- K0: xx[b,n] = sum_c x[b,c,n]^2 ----------------
__global__ void k_xx(const float* __restrict__ x, float* __restrict__ xx) {
  int t = blockIdx.x * 256 + threadIdx.x;          // [0, B*N)
  int b = t >> 12, n = t & (NPTS - 1);
  const float* xp = x + ((size_t)b * CH * NPTS) + n;
  float s = 0.f;
#pragma unroll
  for (int c = 0; c < CH; ++c) { float v = xp[(size_t)c * NPTS]; s = fmaf(v, v, s); }
  xx[t] = s;
}

// ---------------- K2: P'[t,o], Q'[t,o] ----------------
__global__ void k_pq(const float* __restrict__ x, const float* __restrict__ W,
                     const float* __restrict__ gamma, const float* __restrict__ beta,
                     const float* __restrict__ rmean, const float* __restrict__ rvar,
                     float* __restrict__ P, float* __restrict__ Q) {
  __shared__ float Ws1[CH * CH];   // [c][o], W1*inv
  __shared__ float Wsd[CH * CH];   // [c][o], (W2-W1)*inv
  int tid = threadIdx.x;
  for (int i = tid; i < CH * CH; i += 256) {
    int o = i & 63, c = i >> 6;
    float s = gamma[o] * rsqrtf(rvar[o] + EPSV);
    float w1 = W[o * 128 + c], w2 = W[o * 128 + 64 + c];
    Ws1[c * 64 + o] = w1 * s;
    Wsd[c * 64 + o] = (w2 - w1) * s;
  }
  __syncthreads();
  int o = tid & 63, ng = tid >> 6;
  float s = gamma[o] * rsqrtf(rvar[o] + EPSV);
  float shift = beta[o] - rmean[o] * s;
  int base = blockIdx.x * 16;
  for (int rp = 0; rp < 4; ++rp) {
    int t = base + rp * 4 + ng;                    // row in [0, B*N)
    int b = t >> 12, n = t & (NPTS - 1);
    const float* xp = x + ((size_t)b * CH * NPTS) + n;
    float accp = 0.f, accq = 0.f;
#pragma unroll 8
    for (int c = 0; c < CH; ++c) {
      float xv = xp[(size_t)c * NPTS];
      accp = fmaf(xv, Ws1[c * 64 + o], accp);
      accq = fmaf(xv, Wsd[c * 64 + o], accq);
    }
    P[(size_t)t * 64 + o] = accp;
    Q[(size_t)t * 64 + o] = accq + shift;
  }
}

// ---------------- K1 helpers ----------------
// async global->LDS, 16B per lane. LDS dest = wave-uniform base + lane*16.
__device__ __forceinline__ void gload_lds16(const float* g, float* l) {
  __builtin_amdgcn_global_load_lds(
      (const __attribute__((address_space(1))) void*)g,
      (__attribute__((address_space(3))) void*)l, 16, 0, 0);
}

// stage one 64ch x 128col B-tile (32 KB) async; no VGPR round-trip.
__device__ __forceinline__ void stage_b(const float* xb, int mcol, float* Bdst,
                                        int w, int lane) {
#pragma unroll
  for (int k = 0; k < 8; ++k) {
    int q = w + 4 * k;
    int c = 2 * q + (lane >> 5);
    int cm = (lane & 31) << 2;
    gload_lds16(xb + (size_t)c * NPTS + mcol + cm, Bdst + q * 256);
  }
}

// packed fp32 fma: element-wise IEEE fma -> bit-identical to scalar chain
__device__ __forceinline__ v2f fma2(float a, v2f b, v2f c) {
#if __has_builtin(__builtin_elementwise_fma)
  v2f av; av.x = a; av.y = a;
  return __builtin_elementwise_fma(av, b, c);
#else
  v2f r; r.x = fmaf(a, b.x, c.x); r.y = fmaf(a, b.y, c.y); return r;
#endif
}

// ballot-gated serial insert with in-loop threshold tightening.
// Pruned candidates are exactly those that would land below lane 19; list
// entries never move up, so the emitted top-20 is identical to the
// non-pruned version (proof: insertions only push elements down).
__device__ __forceinline__ void insert_group(float d, int mg, int lane,
                                             float& vr, int& ir, float& th) {
  unsigned long long hit = __ballot(d > th);
  while (hit) {
    int j = __builtin_ctzll(hit);
    hit &= hit - 1;
    float cv = __shfl(d, j);
    int cm = mg + j;
    unsigned long long km = __ballot(vr >= cv);    // existing equals stay above
    int cnt = __popcll(km);
    float sv = __shfl_up(vr, 1);
    int si = __shfl_up(ir, 1);
    if (lane >= cnt) {
      vr = (lane == cnt) ? cv : sv;
      ir = (lane == cnt) ? cm : si;
    }
    th = __shfl(vr, KNN - 1);                      // refreshed 20th-best
    if (hit) hit &= __ballot(d > th);              // prune sub-threshold hits
  }
}

// bitonic sort of 64 (d, col=lane) pairs across the wave, descending by d,
// ties -> lower col first. Serial insertion of 64 elements into the empty
// 64-deep list is exactly a full sort with these tie semantics, so the lane
// state after seeding is bit-identical to the streaming path.
__device__ __forceinline__ void seed_sort(float d, int lane,
                                          float& vr, int& ir, float& th) {
  float v = d; int ix = lane;
#pragma unroll
  for (int k = 2; k <= 64; k <<= 1) {
#pragma unroll
    for (int j = k >> 1; j > 0; j >>= 1) {
      float pv = __shfl_xor(v, j);
      int   pi = __shfl_xor(ix, j);
      bool lower = (lane & j) == 0;
      bool desc  = (lane & k) == 0;                // block direction
      bool mineBefore = (v > pv) || (v == pv && ix < pi);
      bool keep = (mineBefore == (lower == desc));
      v  = keep ? v  : pv;
      ix = keep ? ix : pi;
    }
  }
  vr = v; ir = ix; th = __shfl(v, KNN - 1);
}

// GEMM (16 rows x 2 cols per thread, lane==col within each 64-group) +
// register-direct selection. R2 chassis: LDS As + async double-buffered B,
// 256 threads, 2 blocks/CU. fp op order per output element identical to all
// prior passing kernels -> d values bit-identical.
template <bool SEED>
__device__ __forceinline__ void tile_work(const float* Bc, const float* As,
                                          const float* xxb, int m0, int w, int lane,
                                          const float (&xnr)[16],
                                          float (&val)[16], int (&idx)[16],
                                          float (&thd)[16],
                                          const float* stage_src, int stage_mcol,
                                          float* stage_dst) {
  // xm loads first so their vmcnt-consume doesn't wait on the stage below
  float xm0 = xxb[m0 + lane];
  float xm1 = xxb[m0 + 64 + lane];

  // issue next-tile async stage; GEMM+selection covers its latency.
  if (stage_dst) stage_b(stage_src, stage_mcol, stage_dst, w, lane);

  const float* Aw = As + 16 * w;

  v2f acc[16];
#pragma unroll
  for (int r = 0; r < 16; ++r) { acc[r].x = 0.f; acc[r].y = 0.f; }

#pragma unroll 4
  for (int c = 0; c < CH; ++c) {
    float4 A0 = *(const float4*)(Aw + c * 64);
    float4 A1 = *(const float4*)(Aw + c * 64 + 4);
    float4 A2 = *(const float4*)(Aw + c * 64 + 8);
    float4 A3 = *(const float4*)(Aw + c * 64 + 12);
    v2f bb; bb.x = Bc[c * 128 + lane]; bb.y = Bc[c * 128 + 64 + lane];
    acc[0]  = fma2(A0.x, bb, acc[0]);
    acc[1]  = fma2(A0.y, bb, acc[1]);
    acc[2]  = fma2(A0.z, bb, acc[2]);
    acc[3]  = fma2(A0.w, bb, acc[3]);
    acc[4]  = fma2(A1.x, bb, acc[4]);
    acc[5]  = fma2(A1.y, bb, acc[5]);
    acc[6]  = fma2(A1.z, bb, acc[6]);
    acc[7]  = fma2(A1.w, bb, acc[7]);
    acc[8]  = fma2(A2.x, bb, acc[8]);
    acc[9]  = fma2(A2.y, bb, acc[9]);
    acc[10] = fma2(A2.z, bb, acc[10]);
    acc[11] = fma2(A2.w, bb, acc[11]);
    acc[12] = fma2(A3.x, bb, acc[12]);
    acc[13] = fma2(A3.y, bb, acc[13]);
    acc[14] = fma2(A3.z, bb, acc[14]);
    acc[15] = fma2(A3.w, bb, acc[15]);
  }

#pragma unroll
  for (int r = 0; r < 16; ++r) {
    float d0 = (2.f * acc[r].x - xnr[r]) - xm0;
    if constexpr (SEED) {
      seed_sort(d0, lane, val[r], idx[r], thd[r]);  // m0 == 0: col == lane
    } else {
      insert_group(d0, m0, lane, val[r], idx[r], thd[r]);
    }
    float d1 = (2.f * acc[r].y - xnr[r]) - xm1;
    insert_group(d1, m0 + 64, lane, val[r], idx[r], thd[r]);
  }
}

// ---------------- K1: fused distance-GEMM + register-direct top-20 ----------
// LDS = As 16KB + B0 32KB + B1 32KB = 80KB -> 2 blocks/CU.
__launch_bounds__(256, 2)
__global__ void k_knn(const float* __restrict__ x, const float* __restrict__ xx,
                      int* __restrict__ idxout) {
  __shared__ float As[64 * 64];
  __shared__ float B0[64 * 128];
  __shared__ float B1[64 * 128];
  int tid = threadIdx.x;
  int nb = blockIdx.x, b = blockIdx.y;
  int n0 = nb * 64;
  const float* xb = x + (size_t)b * CH * NPTS;
  const float* xxb = xx + b * NPTS;
  int lane = tid & 63;
  int w = tid >> 6;

  // stage B tile 0 async
  stage_b(xb, 0, B0, w, lane);

  // stage A-tile (64 ch x 64 rows)
#pragma unroll
  for (int k = 0; k < 4; ++k) {
    int chunk = tid + 256 * k;                     // 0..1023
    int c = chunk >> 4, cn = (chunk & 15) << 2;
    *(float4*)(As + c * 64 + cn) = *(const float4*)(xb + (size_t)c * NPTS + n0 + cn);
  }

  float xnr[16];
#pragma unroll
  for (int r = 0; r < 16; ++r) xnr[r] = xxb[n0 + 16 * w + r];

  float val[16]; int idx[16]; float thd[16];
#pragma unroll
  for (int r = 0; r < 16; ++r) { val[r] = NEG_INF; idx[r] = 0; thd[r] = NEG_INF; }

  __syncthreads();                                 // drains vmcnt: B0 + As ready

  // tile 0: seeded selection; stages tile 1 -> B1
  tile_work<true>(B0, As, xxb, 0, w, lane, xnr, val, idx, thd, xb, 128, B1);
  __syncthreads();

#pragma unroll 1
  for (int mt = 1; mt < 31; mt += 2) {             // pairs (1,2)...(29,30)
    tile_work<false>(B1, As, xxb, mt * 128, w, lane, xnr, val, idx, thd,
                     xb, (mt + 1) * 128, B0);
    __syncthreads();
    tile_work<false>(B0, As, xxb, (mt + 1) * 128, w, lane, xnr, val, idx, thd,
                     xb, (mt + 2) * 128, B1);
    __syncthreads();
  }
  // tail: tile 31 from B1, no stage
  tile_work<false>(B1, As, xxb, 31 * 128, w, lane, xnr, val, idx, thd,
                   xb, 0, nullptr);

  // emit: lane l (<20) holds l-th best index for row 16w+r
#pragma unroll
  for (int r = 0; r < 16; ++r) {
    int n = n0 + 16 * w + r;
    if (lane < KNN) idxout[(size_t)(b * NPTS + n) * KNN + lane] = idx[r];
  }
}

// ---------------- K3: gather + max + leaky, transpose to (B,O,N) ----------------
__global__ void k_out(const float* __restrict__ P, const float* __restrict__ Q,
                      const int* __restrict__ idx, float* __restrict__ out) {
  __shared__ float T[64 * 65];
  int tid = threadIdx.x;
  int nb = blockIdx.x, b = blockIdx.y;
  int n0 = nb * 64;
  int o = tid & 63, ng = tid >> 6;
  const float* Pb = P + (size_t)b * NPTS * 64;
  for (int p = 0; p < 16; ++p) {
    int nl = p * 4 + ng;
    int n = n0 + nl;
    const int* ip = idx + (size_t)(b * NPTS + n) * KNN;
    float mx = NEG_INF;
#pragma unroll
    for (int k = 0; k < KNN; ++k) {
      int id = ip[k];
      float v = Pb[(size_t)id * 64 + o];
      mx = fmaxf(mx, v);
    }
    float z = mx + Q[(size_t)(b * NPTS + n) * 64 + o];
    z = (z >= 0.f) ? z : NEG_SLOPE * z;
    T[o * 65 + nl] = z;
  }
  __syncthreads();
  float* ob = out + (size_t)b * 64 * NPTS + n0;
  int nl = tid & 63;
  for (int w = 0; w < 16; ++w) {
    int oo = w * 4 + ng;
    ob[(size_t)oo * NPTS + nl] = T[oo * 65 + nl];
  }
}

extern "C" void kernel_launch(void* const* d_in, const int* in_sizes, int n_in,
                              void* d_out, int out_size, void* d_ws, size_t ws_size,
                              hipStream_t stream) {
  const float* x     = (const float*)d_in[0];
  const float* W     = (const float*)d_in[1];
  const float* gamma = (const float*)d_in[2];
  const float* beta  = (const float*)d_in[3];
  const float* rmean = (const float*)d_in[4];
  const float* rvar  = (const float*)d_in[5];
  float* out = (float*)d_out;

  float* xx = (float*)d_ws;                        // 32768 floats
  float* P  = xx + 32768;                          // 2097152 floats
  float* Q  = P + 2097152;                         // 2097152 floats
  int*   idx = (int*)(Q + 2097152);                // 655360 ints

  k_xx<<<BATCH * NPTS / 256, 256, 0, stream>>>(x, xx);
  k_pq<<<BATCH * NPTS / 16, 256, 0, stream>>>(x, W, gamma, beta, rmean, rvar, P, Q);
  k_knn<<<dim3(NPTS / 64, BATCH), 256, 0, stream>>>(x, xx, idx);
  k_out<<<dim3(NPTS / 64, BATCH), 256, 0, stream>>>(P, Q, idx, out);
}

// Round 7
// 648.498 us; speedup vs baseline: 1.4405x; 1.0350x over previous
//
#include <hip/hip_runtime.h>

#define NPTS 4096
#define CH 64
#define BATCH 8
#define KNN 20
#define NEG_SLOPE 0.2f
#define EPSV 1e-5f
#define NEG_INF (-3.4e38f)

typedef float v2f __attribute__((ext_vector_type(2)));

// ---------------- K0: xx[b,n] = sum_c x[b,c,n]^2 ----------------
__global__ void k_xx(const float* __restrict__ x, float* __restrict__ xx) {
  int t = blockIdx.x * 256 + threadIdx.x;          // [0, B*N)
  int b = t >> 12, n = t & (NPTS - 1);
  const float* xp = x + ((size_t)b * CH * NPTS) + n;
  float s = 0.f;
#pragma unroll
  for (int c = 0; c < CH; ++c) { float v = xp[(size_t)c * NPTS]; s = fmaf(v, v, s); }
  xx[t] = s;
}

// ---------------- K2: P'[t,o], Q'[t,o] ----------------
__global__ void k_pq(const float* __restrict__ x, const float* __restrict__ W,
                     const float* __restrict__ gamma, const float* __restrict__ beta,
                     const float* __restrict__ rmean, const float* __restrict__ rvar,
                     float* __restrict__ P, float* __restrict__ Q) {
  __shared__ float Ws1[CH * CH];   // [c][o], W1*inv
  __shared__ float Wsd[CH * CH];   // [c][o], (W2-W1)*inv
  int tid = threadIdx.x;
  for (int i = tid; i < CH * CH; i += 256) {
    int o = i & 63, c = i >> 6;
    float s = gamma[o] * rsqrtf(rvar[o] + EPSV);
    float w1 = W[o * 128 + c], w2 = W[o * 128 + 64 + c];
    Ws1[c * 64 + o] = w1 * s;
    Wsd[c * 64 + o] = (w2 - w1) * s;
  }
  __syncthreads();
  int o = tid & 63, ng = tid >> 6;
  float s = gamma[o] * rsqrtf(rvar[o] + EPSV);
  float shift = beta[o] - rmean[o] * s;
  int base = blockIdx.x * 16;
  for (int rp = 0; rp < 4; ++rp) {
    int t = base + rp * 4 + ng;                    // row in [0, B*N)
    int b = t >> 12, n = t & (NPTS - 1);
    const float* xp = x + ((size_t)b * CH * NPTS) + n;
    float accp = 0.f, accq = 0.f;
#pragma unroll 8
    for (int c = 0; c < CH; ++c) {
      float xv = xp[(size_t)c * NPTS];
      accp = fmaf(xv, Ws1[c * 64 + o], accp);
      accq = fmaf(xv, Wsd[c * 64 + o], accq);
    }
    P[(size_t)t * 64 + o] = accp;
    Q[(size_t)t * 64 + o] = accq + shift;
  }
}

// ---------------- K1 helpers ----------------
// async global->LDS, 16B per lane. LDS dest = wave-uniform base + lane*16.
__device__ __forceinline__ void gload_lds16(const float* g, float* l) {
  __builtin_amdgcn_global_load_lds(
      (const __attribute__((address_space(1))) void*)g,
      (__attribute__((address_space(3))) void*)l, 16, 0, 0);
}

// stage one 64ch x 256col B-tile (64 KB) async. One wave-instr covers one
// row (256 floats = 64 lanes x 16B): lane l -> floats 4l..4l+3.
// Wave w handles rows w, w+8, ..., w+56. LDS base wave-uniform.
__device__ __forceinline__ void stage_b(const float* xb, int mcol, float* Bdst,
                                        int w, int lane) {
#pragma unroll
  for (int k = 0; k < 8; ++k) {
    int c = w + 8 * k;
    gload_lds16(xb + (size_t)c * NPTS + mcol + 4 * lane, Bdst + c * 256);
  }
}

// packed fp32 fma: element-wise IEEE fma -> bit-identical to scalar chain
__device__ __forceinline__ v2f fma2(float a, v2f b, v2f c) {
#if __has_builtin(__builtin_elementwise_fma)
  v2f av; av.x = a; av.y = a;
  return __builtin_elementwise_fma(av, b, c);
#else
  v2f r; r.x = fmaf(a, b.x, c.x); r.y = fmaf(a, b.y, c.y); return r;
#endif
}

// ballot-gated serial insert with in-loop threshold tightening (R5, passed).
__device__ __forceinline__ void insert_group(float d, int mg, int lane,
                                             float& vr, int& ir, float& th) {
  unsigned long long hit = __ballot(d > th);
  while (hit) {
    int j = __builtin_ctzll(hit);
    hit &= hit - 1;
    float cv = __shfl(d, j);
    int cm = mg + j;
    unsigned long long km = __ballot(vr >= cv);    // existing equals stay above
    int cnt = __popcll(km);
    float sv = __shfl_up(vr, 1);
    int si = __shfl_up(ir, 1);
    if (lane >= cnt) {
      vr = (lane == cnt) ? cv : sv;
      ir = (lane == cnt) ? cm : si;
    }
    th = __shfl(vr, KNN - 1);                      // refreshed 20th-best
    if (hit) hit &= __ballot(d > th);              // prune sub-threshold hits
  }
}

// bitonic seed sort (R5, passed): 64 (d, col=lane) pairs, d desc, ties ->
// lower col. Equals serial insertion into the empty list -> bit-identical.
__device__ __forceinline__ void seed_sort(float d, int lane,
                                          float& vr, int& ir, float& th) {
  float v = d; int ix = lane;
#pragma unroll
  for (int k = 2; k <= 64; k <<= 1) {
#pragma unroll
    for (int j = k >> 1; j > 0; j >>= 1) {
      float pv = __shfl_xor(v, j);
      int   pi = __shfl_xor(ix, j);
      bool lower = (lane & j) == 0;
      bool desc  = (lane & k) == 0;                // block direction
      bool mineBefore = (v > pv) || (v == pv && ix < pi);
      bool keep = (mineBefore == (lower == desc));
      v  = keep ? v  : pv;
      ix = keep ? ix : pi;
    }
  }
  vr = v; ir = ix; th = __shfl(v, KNN - 1);
}

// GEMM (8 rows x 4 cols per thread; lane==col within each 64-group) +
// register-direct selection. R4's math (passed) + R5's selection (passed).
// Candidate order: groups g=0..3 ascending, ctz-ascending within group ->
// global candidate stream identical to all prior rounds -> bit-identical.
template <bool SEED>
__device__ __forceinline__ void tile_work(const float* Bc, const float* As,
                                          const float* xxb, int m0, int w, int lane,
                                          const float (&xnr)[8],
                                          float (&val)[8], int (&idx)[8],
                                          float (&thd)[8]) {
  float xm[4];
#pragma unroll
  for (int g = 0; g < 4; ++g) xm[g] = xxb[m0 + 64 * g + lane];

  const float* Aw = As + 8 * w;

  v2f accA[8], accB[8];
#pragma unroll
  for (int r = 0; r < 8; ++r) {
    accA[r].x = 0.f; accA[r].y = 0.f; accB[r].x = 0.f; accB[r].y = 0.f;
  }

#pragma unroll 4
  for (int c = 0; c < CH; ++c) {
    float4 A0 = *(const float4*)(Aw + c * 64);       // rows 8w..8w+3 (broadcast)
    float4 A1 = *(const float4*)(Aw + c * 64 + 4);   // rows 8w+4..8w+7
    v2f bbA, bbB;
    bbA.x = Bc[c * 256 + lane];
    bbA.y = Bc[c * 256 + 64 + lane];
    bbB.x = Bc[c * 256 + 128 + lane];
    bbB.y = Bc[c * 256 + 192 + lane];
    accA[0] = fma2(A0.x, bbA, accA[0]);  accB[0] = fma2(A0.x, bbB, accB[0]);
    accA[1] = fma2(A0.y, bbA, accA[1]);  accB[1] = fma2(A0.y, bbB, accB[1]);
    accA[2] = fma2(A0.z, bbA, accA[2]);  accB[2] = fma2(A0.z, bbB, accB[2]);
    accA[3] = fma2(A0.w, bbA, accA[3]);  accB[3] = fma2(A0.w, bbB, accB[3]);
    accA[4] = fma2(A1.x, bbA, accA[4]);  accB[4] = fma2(A1.x, bbB, accB[4]);
    accA[5] = fma2(A1.y, bbA, accA[5]);  accB[5] = fma2(A1.y, bbB, accB[5]);
    accA[6] = fma2(A1.z, bbA, accA[6]);  accB[6] = fma2(A1.z, bbB, accB[6]);
    accA[7] = fma2(A1.w, bbA, accA[7]);  accB[7] = fma2(A1.w, bbB, accB[7]);
  }

#pragma unroll
  for (int r = 0; r < 8; ++r) {
    float d0 = (2.f * accA[r].x - xnr[r]) - xm[0];
    if constexpr (SEED) {
      seed_sort(d0, lane, val[r], idx[r], thd[r]);  // m0==0: col == lane
    } else {
      insert_group(d0, m0, lane, val[r], idx[r], thd[r]);
    }
    float d1 = (2.f * accA[r].y - xnr[r]) - xm[1];
    insert_group(d1, m0 + 64, lane, val[r], idx[r], thd[r]);
    float d2 = (2.f * accB[r].x - xnr[r]) - xm[2];
    insert_group(d2, m0 + 128, lane, val[r], idx[r], thd[r]);
    float d3 = (2.f * accB[r].y - xnr[r]) - xm[3];
    insert_group(d3, m0 + 192, lane, val[r], idx[r], thd[r]);
  }
}

// ---------------- K1: fused distance-GEMM + register-direct top-20 ----------
// 512 threads = 8 waves; wave w owns rows 8w..8w+7; tile 64 x 256.
// LDS = As 16KB + Bs 64KB = 80KB (SINGLE-buffered) -> 2 blocks/CU ->
// 16 waves/CU = 4 waves/SIMD (2x all prior rounds, which were grid-capped
// at 2/SIMD). The single-buffer stage stall (~700 cyc/tile) is covered by
// the co-resident block's compute (~7k cyc/tile). 256-col tiles halve the
// broadcast A ds_read traffic vs 128-col (16 tiles instead of 32).
__launch_bounds__(512, 3)
__global__ void k_knn(const float* __restrict__ x, const float* __restrict__ xx,
                      int* __restrict__ idxout) {
  __shared__ float As[64 * 64];
  __shared__ float Bs[64 * 256];
  int tid = threadIdx.x;
  int nb = blockIdx.x, b = blockIdx.y;
  int n0 = nb * 64;
  const float* xb = x + (size_t)b * CH * NPTS;
  const float* xxb = xx + b * NPTS;
  int lane = tid & 63;
  int w = tid >> 6;

  // stage B tile 0 async (64 KB)
  stage_b(xb, 0, Bs, w, lane);

  // stage A-tile [c][n]: 4096 floats, 512 threads x 8 floats
  {
    int c = tid >> 3, n4 = (tid & 7) << 3;
    float4 v0 = *(const float4*)(xb + (size_t)c * NPTS + n0 + n4);
    float4 v1 = *(const float4*)(xb + (size_t)c * NPTS + n0 + n4 + 4);
    *(float4*)(As + c * 64 + n4) = v0;
    *(float4*)(As + c * 64 + n4 + 4) = v1;
  }

  float xnr[8];
#pragma unroll
  for (int r = 0; r < 8; ++r) xnr[r] = xxb[n0 + 8 * w + r];

  float val[8]; int idx[8]; float thd[8];
#pragma unroll
  for (int r = 0; r < 8; ++r) { val[r] = NEG_INF; idx[r] = 0; thd[r] = NEG_INF; }

  __syncthreads();                                 // Bs(0) + As ready (vmcnt drained)

  // tile 0: seeded selection
  tile_work<true>(Bs, As, xxb, 0, w, lane, xnr, val, idx, thd);

#pragma unroll 1
  for (int mt = 1; mt < NPTS / 256; ++mt) {
    __syncthreads();                               // all readers of Bs done
    stage_b(xb, mt * 256, Bs, w, lane);            // overwrite with tile mt
    __syncthreads();                               // Bs(mt) ready
    tile_work<false>(Bs, As, xxb, mt * 256, w, lane, xnr, val, idx, thd);
  }

  // emit: lane l (<20) holds l-th best index for row 8w+r
#pragma unroll
  for (int r = 0; r < 8; ++r) {
    int n = n0 + 8 * w + r;
    if (lane < KNN) idxout[(size_t)(b * NPTS + n) * KNN + lane] = idx[r];
  }
}

// ---------------- K3: gather + max + leaky, transpose to (B,O,N) ----------------
__global__ void k_out(const float* __restrict__ P, const float* __restrict__ Q,
                      const int* __restrict__ idx, float* __restrict__ out) {
  __shared__ float T[64 * 65];
  int tid = threadIdx.x;
  int nb = blockIdx.x, b = blockIdx.y;
  int n0 = nb * 64;
  int o = tid & 63, ng = tid >> 6;
  const float* Pb = P + (size_t)b * NPTS * 64;
  for (int p = 0; p < 16; ++p) {
    int nl = p * 4 + ng;
    int n = n0 + nl;
    const int* ip = idx + (size_t)(b * NPTS + n) * KNN;
    float mx = NEG_INF;
#pragma unroll
    for (int k = 0; k < KNN; ++k) {
      int id = ip[k];
      float v = Pb[(size_t)id * 64 + o];
      mx = fmaxf(mx, v);
    }
    float z = mx + Q[(size_t)(b * NPTS + n) * 64 + o];
    z = (z >= 0.f) ? z : NEG_SLOPE * z;
    T[o * 65 + nl] = z;
  }
  __syncthreads();
  float* ob = out + (size_t)b * 64 * NPTS + n0;
  int nl = tid & 63;
  for (int w = 0; w < 16; ++w) {
    int oo = w * 4 + ng;
    ob[(size_t)oo * NPTS + nl] = T[oo * 65 + nl];
  }
}

extern "C" void kernel_launch(void* const* d_in, const int* in_sizes, int n_in,
                              void* d_out, int out_size, void* d_ws, size_t ws_size,
                              hipStream_t stream) {
  const float* x     = (const float*)d_in[0];
  const float* W     = (const float*)d_in[1];
  const float* gamma = (const float*)d_in[2];
  const float* beta  = (const float*)d_in[3];
  const float* rmean = (const float*)d_in[4];
  const float* rvar  = (const float*)d_in[5];
  float* out = (float*)d_out;

  float* xx = (float*)d_ws;                        // 32768 floats
  float* P  = xx + 32768;                          // 2097152 floats
  float* Q  = P + 2097152;                         // 2097152 floats
  int*   idx = (int*)(Q + 2097152);                // 655360 ints

  k_xx<<<BATCH * NPTS / 256, 256, 0, stream>>>(x, xx);
  k_pq<<<BATCH * NPTS / 16, 256, 0, stream>>>(x, W, gamma, beta, rmean, rvar, P, Q);
  k_knn<<<dim3(NPTS / 64, BATCH), 512, 0, stream>>>(x, xx, idx);
  k_out<<<dim3(NPTS / 64, BATCH), 256, 0, stream>>>(P, Q, idx, out);
}

// Round 8
// 521.266 us; speedup vs baseline: 1.7921x; 1.2441x over previous
//
#include <hip/hip_runtime.h>

#define NPTS 4096
#define CH 64
#define BATCH 8
#define KNN 20
#define NEG_SLOPE 0.2f
#define EPSV 1e-5f
#define NEG_INF (-3.4e38f)

typedef float v2f __attribute__((ext_vector_type(2)));

// ---------------- K0: xx[b,n] = sum_c x[b,c,n]^2 ----------------
__global__ void k_xx(const float* __restrict__ x, float* __restrict__ xx) {
  int t = blockIdx.x * 256 + threadIdx.x;          // [0, B*N)
  int b = t >> 12, n = t & (NPTS - 1);
  const float* xp = x + ((size_t)b * CH * NPTS) + n;
  float s = 0.f;
#pragma unroll
  for (int c = 0; c < CH; ++c) { float v = xp[(size_t)c * NPTS]; s = fmaf(v, v, s); }
  xx[t] = s;
}

// ---------------- K2: P'[t,o], Q'[t,o] ----------------
__global__ void k_pq(const float* __restrict__ x, const float* __restrict__ W,
                     const float* __restrict__ gamma, const float* __restrict__ beta,
                     const float* __restrict__ rmean, const float* __restrict__ rvar,
                     float* __restrict__ P, float* __restrict__ Q) {
  __shared__ float Ws1[CH * CH];   // [c][o], W1*inv
  __shared__ float Wsd[CH * CH];   // [c][o], (W2-W1)*inv
  int tid = threadIdx.x;
  for (int i = tid; i < CH * CH; i += 256) {
    int o = i & 63, c = i >> 6;
    float s = gamma[o] * rsqrtf(rvar[o] + EPSV);
    float w1 = W[o * 128 + c], w2 = W[o * 128 + 64 + c];
    Ws1[c * 64 + o] = w1 * s;
    Wsd[c * 64 + o] = (w2 - w1) * s;
  }
  __syncthreads();
  int o = tid & 63, ng = tid >> 6;
  float s = gamma[o] * rsqrtf(rvar[o] + EPSV);
  float shift = beta[o] - rmean[o] * s;
  int base = blockIdx.x * 16;
  for (int rp = 0; rp < 4; ++rp) {
    int t = base + rp * 4 + ng;                    // row in [0, B*N)
    int b = t >> 12, n = t & (NPTS - 1);
    const float* xp = x + ((size_t)b * CH * NPTS) + n;
    float accp = 0.f, accq = 0.f;
#pragma unroll 8
    for (int c = 0; c < CH; ++c) {
      float xv = xp[(size_t)c * NPTS];
      accp = fmaf(xv, Ws1[c * 64 + o], accp);
      accq = fmaf(xv, Wsd[c * 64 + o], accq);
    }
    P[(size_t)t * 64 + o] = accp;
    Q[(size_t)t * 64 + o] = accq + shift;
  }
}

// ---------------- K1 helpers ----------------
// async global->LDS, 16B per lane. LDS dest = wave-uniform base + lane*16.
__device__ __forceinline__ void gload_lds16(const float* g, float* l) {
  __builtin_amdgcn_global_load_lds(
      (const __attribute__((address_space(1))) void*)g,
      (__attribute__((address_space(3))) void*)l, 16, 0, 0);
}

// stage one 64ch x 256col B-tile (64 KB) async with 16 waves. One wave-instr
// covers one c-row (256 floats = 64 lanes x 16B): lane l -> floats 4l..4l+3.
// Wave w handles rows w, w+16, w+32, w+48. LDS base wave-uniform.
__device__ __forceinline__ void stage_b(const float* xb, int mcol, float* Bdst,
                                        int w, int lane) {
#pragma unroll
  for (int k = 0; k < 4; ++k) {
    int c = w + 16 * k;
    gload_lds16(xb + (size_t)c * NPTS + mcol + 4 * lane, Bdst + c * 256);
  }
}

// packed fp32 fma: element-wise IEEE fma -> bit-identical to scalar chain
__device__ __forceinline__ v2f fma2(float a, v2f b, v2f c) {
#if __has_builtin(__builtin_elementwise_fma)
  v2f av; av.x = a; av.y = a;
  return __builtin_elementwise_fma(av, b, c);
#else
  v2f r; r.x = fmaf(a, b.x, c.x); r.y = fmaf(a, b.y, c.y); return r;
#endif
}

// ballot-gated serial insert with in-loop threshold tightening (R5/R7, passed).
__device__ __forceinline__ void insert_group(float d, int mg, int lane,
                                             float& vr, int& ir, float& th) {
  unsigned long long hit = __ballot(d > th);
  while (hit) {
    int j = __builtin_ctzll(hit);
    hit &= hit - 1;
    float cv = __shfl(d, j);
    int cm = mg + j;
    unsigned long long km = __ballot(vr >= cv);    // existing equals stay above
    int cnt = __popcll(km);
    float sv = __shfl_up(vr, 1);
    int si = __shfl_up(ir, 1);
    if (lane >= cnt) {
      vr = (lane == cnt) ? cv : sv;
      ir = (lane == cnt) ? cm : si;
    }
    th = __shfl(vr, KNN - 1);                      // refreshed 20th-best
    if (hit) hit &= __ballot(d > th);              // prune sub-threshold hits
  }
}

// bitonic seed sort (R5/R7, passed): 64 (d, col=lane) pairs, d desc, ties ->
// lower col. Equals serial insertion into the empty list -> bit-identical.
__device__ __forceinline__ void seed_sort(float d, int lane,
                                          float& vr, int& ir, float& th) {
  float v = d; int ix = lane;
#pragma unroll
  for (int k = 2; k <= 64; k <<= 1) {
#pragma unroll
    for (int j = k >> 1; j > 0; j >>= 1) {
      float pv = __shfl_xor(v, j);
      int   pi = __shfl_xor(ix, j);
      bool lower = (lane & j) == 0;
      bool desc  = (lane & k) == 0;                // block direction
      bool mineBefore = (v > pv) || (v == pv && ix < pi);
      bool keep = (mineBefore == (lower == desc));
      v  = keep ? v  : pv;
      ix = keep ? ix : pi;
    }
  }
  vr = v; ir = ix; th = __shfl(v, KNN - 1);
}

// GEMM (8 rows x 4 cols per thread; lane==col within each 64-group) +
// register-direct selection. Identical per-wave geometry/math to R7 (passed);
// only the A-tile leading dimension changes (128-row block). Candidate order:
// groups g=0..3 ascending, ctz-ascending within group -> bit-identical.
template <bool SEED>
__device__ __forceinline__ void tile_work(const float* Bc, const float* As,
                                          const float* xxb, int m0, int w, int lane,
                                          const float (&xnr)[8],
                                          float (&val)[8], int (&idx)[8],
                                          float (&thd)[8]) {
  float xm[4];
#pragma unroll
  for (int g = 0; g < 4; ++g) xm[g] = xxb[m0 + 64 * g + lane];

  const float* Aw = As + 8 * w;                    // rows 8w..8w+7, LDA=128

  v2f accA[8], accB[8];
#pragma unroll
  for (int r = 0; r < 8; ++r) {
    accA[r].x = 0.f; accA[r].y = 0.f; accB[r].x = 0.f; accB[r].y = 0.f;
  }

#pragma unroll 4
  for (int c = 0; c < CH; ++c) {
    float4 A0 = *(const float4*)(Aw + c * 128);      // rows 8w..8w+3 (broadcast)
    float4 A1 = *(const float4*)(Aw + c * 128 + 4);  // rows 8w+4..8w+7
    v2f bbA, bbB;
    bbA.x = Bc[c * 256 + lane];
    bbA.y = Bc[c * 256 + 64 + lane];
    bbB.x = Bc[c * 256 + 128 + lane];
    bbB.y = Bc[c * 256 + 192 + lane];
    accA[0] = fma2(A0.x, bbA, accA[0]);  accB[0] = fma2(A0.x, bbB, accB[0]);
    accA[1] = fma2(A0.y, bbA, accA[1]);  accB[1] = fma2(A0.y, bbB, accB[1]);
    accA[2] = fma2(A0.z, bbA, accA[2]);  accB[2] = fma2(A0.z, bbB, accB[2]);
    accA[3] = fma2(A0.w, bbA, accA[3]);  accB[3] = fma2(A0.w, bbB, accB[3]);
    accA[4] = fma2(A1.x, bbA, accA[4]);  accB[4] = fma2(A1.x, bbB, accB[4]);
    accA[5] = fma2(A1.y, bbA, accA[5]);  accB[5] = fma2(A1.y, bbB, accB[5]);
    accA[6] = fma2(A1.z, bbA, accA[6]);  accB[6] = fma2(A1.z, bbB, accB[6]);
    accA[7] = fma2(A1.w, bbA, accA[7]);  accB[7] = fma2(A1.w, bbB, accB[7]);
  }

#pragma unroll
  for (int r = 0; r < 8; ++r) {
    float d0 = (2.f * accA[r].x - xnr[r]) - xm[0];
    if constexpr (SEED) {
      seed_sort(d0, lane, val[r], idx[r], thd[r]);  // m0==0: col == lane
    } else {
      insert_group(d0, m0, lane, val[r], idx[r], thd[r]);
    }
    float d1 = (2.f * accA[r].y - xnr[r]) - xm[1];
    insert_group(d1, m0 + 64, lane, val[r], idx[r], thd[r]);
    float d2 = (2.f * accB[r].x - xnr[r]) - xm[2];
    insert_group(d2, m0 + 128, lane, val[r], idx[r], thd[r]);
    float d3 = (2.f * accB[r].y - xnr[r]) - xm[3];
    insert_group(d3, m0 + 192, lane, val[r], idx[r], thd[r]);
  }
}

// ---------------- K1: fused distance-GEMM + register-direct top-20 ----------
// 1024 threads = 16 waves; wave w owns rows 8w..8w+7; tile 128 rows x 256 cols.
// LDS = As[64][128] 32KB + Bs 64KB = 96KB -> 1 block/CU, but that block is
// 16 waves = 4 waves/SIMD (2x every prior round, which all ran 8 waves/CU —
// R7 showed 2x80KB fails the 160KB exact fit). Grid = 32x8 = 256 blocks =
// exactly 1/CU. Per-CU LDS traffic unchanged vs R7; latency hiding doubled.
__launch_bounds__(1024, 4)
__global__ void k_knn(const float* __restrict__ x, const float* __restrict__ xx,
                      int* __restrict__ idxout) {
  __shared__ float As[64 * 128];                   // [c][n], LDA=128
  __shared__ float Bs[64 * 256];
  int tid = threadIdx.x;
  int nb = blockIdx.x, b = blockIdx.y;
  int n0 = nb * 128;
  const float* xb = x + (size_t)b * CH * NPTS;
  const float* xxb = xx + b * NPTS;
  int lane = tid & 63;
  int w = tid >> 6;                                // 0..15

  // stage B tile 0 async (64 KB)
  stage_b(xb, 0, Bs, w, lane);

  // stage A-tile [c][n]: 8192 floats, 1024 threads x 8 floats
  {
    int c = tid >> 4, n8 = (tid & 15) << 3;
    float4 v0 = *(const float4*)(xb + (size_t)c * NPTS + n0 + n8);
    float4 v1 = *(const float4*)(xb + (size_t)c * NPTS + n0 + n8 + 4);
    *(float4*)(As + c * 128 + n8) = v0;
    *(float4*)(As + c * 128 + n8 + 4) = v1;
  }

  float xnr[8];
#pragma unroll
  for (int r = 0; r < 8; ++r) xnr[r] = xxb[n0 + 8 * w + r];

  float val[8]; int idx[8]; float thd[8];
#pragma unroll
  for (int r = 0; r < 8; ++r) { val[r] = NEG_INF; idx[r] = 0; thd[r] = NEG_INF; }

  __syncthreads();                                 // Bs(0) + As ready (vmcnt drained)

  // tile 0: seeded selection
  tile_work<true>(Bs, As, xxb, 0, w, lane, xnr, val, idx, thd);

#pragma unroll 1
  for (int mt = 1; mt < NPTS / 256; ++mt) {
    __syncthreads();                               // all readers of Bs done
    stage_b(xb, mt * 256, Bs, w, lane);            // overwrite with tile mt
    __syncthreads();                               // Bs(mt) ready
    tile_work<false>(Bs, As, xxb, mt * 256, w, lane, xnr, val, idx, thd);
  }

  // emit: lane l (<20) holds l-th best index for row 8w+r
#pragma unroll
  for (int r = 0; r < 8; ++r) {
    int n = n0 + 8 * w + r;
    if (lane < KNN) idxout[(size_t)(b * NPTS + n) * KNN + lane] = idx[r];
  }
}

// ---------------- K3: gather + max + leaky, transpose to (B,O,N) ----------------
__global__ void k_out(const float* __restrict__ P, const float* __restrict__ Q,
                      const int* __restrict__ idx, float* __restrict__ out) {
  __shared__ float T[64 * 65];
  int tid = threadIdx.x;
  int nb = blockIdx.x, b = blockIdx.y;
  int n0 = nb * 64;
  int o = tid & 63, ng = tid >> 6;
  const float* Pb = P + (size_t)b * NPTS * 64;
  for (int p = 0; p < 16; ++p) {
    int nl = p * 4 + ng;
    int n = n0 + nl;
    const int* ip = idx + (size_t)(b * NPTS + n) * KNN;
    float mx = NEG_INF;
#pragma unroll
    for (int k = 0; k < KNN; ++k) {
      int id = ip[k];
      float v = Pb[(size_t)id * 64 + o];
      mx = fmaxf(mx, v);
    }
    float z = mx + Q[(size_t)(b * NPTS + n) * 64 + o];
    z = (z >= 0.f) ? z : NEG_SLOPE * z;
    T[o * 65 + nl] = z;
  }
  __syncthreads();
  float* ob = out + (size_t)b * 64 * NPTS + n0;
  int nl = tid & 63;
  for (int w = 0; w < 16; ++w) {
    int oo = w * 4 + ng;
    ob[(size_t)oo * NPTS + nl] = T[oo * 65 + nl];
  }
}

extern "C" void kernel_launch(void* const* d_in, const int* in_sizes, int n_in,
                              void* d_out, int out_size, void* d_ws, size_t ws_size,
                              hipStream_t stream) {
  const float* x     = (const float*)d_in[0];
  const float* W     = (const float*)d_in[1];
  const float* gamma = (const float*)d_in[2];
  const float* beta  = (const float*)d_in[3];
  const float* rmean = (const float*)d_in[4];
  const float* rvar  = (const float*)d_in[5];
  float* out = (float*)d_out;

  float* xx = (float*)d_ws;                        // 32768 floats
  float* P  = xx + 32768;                          // 2097152 floats
  float* Q  = P + 2097152;                         // 2097152 floats
  int*   idx = (int*)(Q + 2097152);                // 655360 ints

  k_xx<<<BATCH * NPTS / 256, 256, 0, stream>>>(x, xx);
  k_pq<<<BATCH * NPTS / 16, 256, 0, stream>>>(x, W, gamma, beta, rmean, rvar, P, Q);
  k_knn<<<dim3(NPTS / 128, BATCH), 1024, 0, stream>>>(x, xx, idx);
  k_out<<<dim3(NPTS / 64, BATCH), 256, 0, stream>>>(P, Q, idx, out);
}